// Round 3
// baseline (24.535 us; speedup 1.0000x reference)
//
#include <hip/hip_runtime.h>

// Lennard-Jones periodic pair energy, B=4, N=4096, D=3. Round 3:
// - 128-thread blocks, 32x32 tile triangle, JL=64 j's/block -> 4224 blocks
//   (block queue ~16.5/CU vs residency ~16 => ~3% tail, CUs stay fed)
// - unscaled coords: min-image w = min(|d|, box-|d|), abs folds to modifiers
// - unroll 16 pairs/body, paired accumulators for ILP
// - deterministic 2-kernel reduce (no float atomics)

constexpr int B_ = 4;
constexpr int N_ = 4096;
constexpr int TI = 128;                        // block threads = i-tile size
constexpr int NTILE = N_ / TI;                 // 32
constexpr int NPAIR = NTILE * (NTILE + 1) / 2; // 528 tile-pairs (it<=jt)
constexpr int NSUB = 2;                        // j sub-slices per tile-pair
constexpr int JL = TI / NSUB;                  // 64 j's per block
constexpr int TASKS_PER_B = NPAIR * NSUB;      // 1056
constexpr int NBLK = B_ * TASKS_PER_B;         // 4224

template<bool DIAG>
__device__ __forceinline__ void tile_loop(
    const float (*__restrict__ sj)[JL], float xi0, float xi1, float xi2,
    int selfj, float box, float c2, float& out12, float& out6)
{
    float a12[2] = {0.f, 0.f}, a6[2] = {0.f, 0.f};
    #pragma unroll 4
    for (int j4 = 0; j4 < JL; j4 += 4) {
        float jx[4], jy[4], jz[4];
        *(float4*)jx = *(const float4*)&sj[0][j4];   // broadcast b128 reads
        *(float4*)jy = *(const float4*)&sj[1][j4];
        *(float4*)jz = *(const float4*)&sj[2][j4];
        #pragma unroll
        for (int u = 0; u < 4; ++u) {
            float dx = jx[u] - xi0;
            float dy = jy[u] - xi1;
            float dz = jz[u] - xi2;
            // min-image: |d| and box-|d| (abs = free VOP3 modifier)
            float wx = fminf(fabsf(dx), box - fabsf(dx));
            float wy = fminf(fabsf(dy), box - fabsf(dy));
            float wz = fminf(fabsf(dz), box - fabsf(dz));
            float r2 = wx * wx;
            r2 = fmaf(wy, wy, r2);
            r2 = fmaf(wz, wz, r2);
            float t  = c2 * __builtin_amdgcn_rcpf(r2);
            float p  = t * t;
            float s6 = p * t;
            if (DIAG) s6 = (selfj == j4 + u) ? 0.f : s6;  // mask self-pair
            a12[u & 1] = fmaf(s6, s6, a12[u & 1]);
            a6[u & 1] += s6;
        }
    }
    out12 = a12[0] + a12[1];
    out6  = a6[0] + a6[1];
}

__global__ __launch_bounds__(TI) void lj_main(
    const float* __restrict__ x, const float* __restrict__ sigma,
    const float* __restrict__ box_p, float* __restrict__ partial)
{
    __shared__ __align__(16) float sj[3][JL];
    const int gid = blockIdx.x;
    const int b   = gid / TASKS_PER_B;
    const int rem = gid % TASKS_PER_B;
    const int pairIdx = rem >> 1;          // / NSUB
    const int sub     = rem & (NSUB - 1);
    // pairIdx -> (it, jt), it<=jt (uniform scalar loop)
    int it = 0, k = pairIdx;
    while (k >= NTILE - it) { k -= NTILE - it; ++it; }
    const int jt = it + k;
    const int tid = threadIdx.x;

    const float box = box_p[0];
    const float sg  = sigma[0];
    const float c2  = sg * sg;

    const float* xb = x + (size_t)b * N_ * 3;

    // stage 64 j's (AoS global -> SoA LDS), 192 contiguous floats
    const float* xj = xb + (jt * TI + sub * JL) * 3;
    #pragma unroll
    for (int kk = tid; kk < JL * 3; kk += TI) sj[kk % 3][kk / 3] = xj[kk];

    const int i = it * TI + tid;
    const float xi0 = xb[i * 3 + 0];
    const float xi1 = xb[i * 3 + 1];
    const float xi2 = xb[i * 3 + 2];
    __syncthreads();

    float s12, s6;
    if (it == jt) {
        tile_loop<true >(sj, xi0, xi1, xi2, tid - sub * JL, box, c2, s12, s6);
    } else {
        tile_loop<false>(sj, xi0, xi1, xi2, -1, box, c2, s12, s6);
    }
    float acc = s12 - s6;
    if (it == jt) acc *= 0.5f;             // diag tile double-counted

    // block reduction (2 waves)
    #pragma unroll
    for (int off = 32; off; off >>= 1) acc += __shfl_down(acc, off);
    __shared__ float wpart[TI / 64];
    if ((tid & 63) == 0) wpart[tid >> 6] = acc;
    __syncthreads();
    if (tid == 0) partial[gid] = wpart[0] + wpart[1];
}

__global__ __launch_bounds__(256) void lj_reduce(
    const float* __restrict__ partial, const float* __restrict__ eps,
    float* __restrict__ out)
{
    const int b = blockIdx.x, t = threadIdx.x;
    float v = 0.f;
    for (int kk = t; kk < TASKS_PER_B; kk += 256) v += partial[b * TASKS_PER_B + kk];
    #pragma unroll
    for (int off = 32; off; off >>= 1) v += __shfl_down(v, off);
    __shared__ float wpart[4];
    if ((t & 63) == 0) wpart[t >> 6] = v;
    __syncthreads();
    if (t == 0) {
        float s = 0.f;
        #pragma unroll
        for (int w = 0; w < 4; ++w) s += wpart[w];
        out[b] = s * (4.0f * eps[0]);      // 4*eps, each pair counted once
    }
}

extern "C" void kernel_launch(void* const* d_in, const int* in_sizes, int n_in,
                              void* d_out, int out_size, void* d_ws, size_t ws_size,
                              hipStream_t stream) {
    const float* x     = (const float*)d_in[0];
    const float* eps   = (const float*)d_in[1];
    const float* sigma = (const float*)d_in[2];
    const float* box   = (const float*)d_in[3];
    float* out = (float*)d_out;
    float* ws  = (float*)d_ws;   // NBLK floats of partials

    lj_main<<<NBLK, TI, 0, stream>>>(x, sigma, box, ws);
    lj_reduce<<<B_, 256, 0, stream>>>(ws, eps, out);
}